// Round 1
// baseline (155.347 us; speedup 1.0000x reference)
//
#include <hip/hip_runtime.h>
#include <stdint.h>
#include <math.h>

// ---------------------------------------------------------------------------
// IID segmentation loss on MI355X.  Round 3.
// R2 counters: corr_gemm 58.8us, MfmaUtil 27%, VALUBusy 25%, Occ 15.8% ->
// latency-bound; occupancy capped at 2 waves/SIMD by acc[5][5]=100 regs/wave.
// R3: re-tile 100 tiles as 10 waves x (2M x 5N) -> acc[2][5]=40 regs,
// 640-thread blocks, 3 waves/SIMD residency. ldsA double-buffered (1 barrier
// per row instead of 2). TY 7->14, grid 512->256: partials 51->26MB, stage1
// read halves. XCD-bijective block swizzle for B-row L2 locality.
// ---------------------------------------------------------------------------

#define PADV 7
#define TS 15
#define KCLS 10
#define HH 224
#define WW 224
#define MD 160
#define NCELL (MD*MD)
#define NBLK 256
#define TY 14
#define AROW 240
#define BSTRIDE 232
#define BPH 240
#define LEPS 1e-16

typedef __attribute__((ext_vector_type(4))) float f32x4;
typedef __attribute__((ext_vector_type(8))) short bf16x8;

__device__ __forceinline__ unsigned short f2bf(float f) {
  union { float f; uint32_t u; } v; v.f = f;
  return (unsigned short)((v.u + 0x7FFFu + ((v.u >> 16) & 1u)) >> 16);
}

__device__ __forceinline__ void glds16(const unsigned short* g, unsigned short* l) {
  __builtin_amdgcn_global_load_lds(
      (const __attribute__((address_space(1))) unsigned int*)g,
      (__attribute__((address_space(3))) unsigned int*)l, 16, 0, 0);
}

// Bpad[cls][yy][x]: cls=b*10+o, yy in [0,240) <-> row=yy-7, x in [0,232).
__global__ __launch_bounds__(256)
void prep_b(const float* __restrict__ xt, unsigned short* __restrict__ bp) {
  const int idx   = blockIdx.x * 256 + threadIdx.x;
  const int rowid = idx / 29;
  const int chunk = idx - rowid * 29;
  const int x0    = chunk * 8;
  const int yy    = rowid % BPH;
  const int cls   = rowid / BPH;
  const int row   = yy - PADV;
  union { unsigned short h[8]; uint4 v; } out;
  if (row >= 0 && row < HH && x0 < WW) {
    const float* src = xt + ((size_t)cls * HH + row) * WW + x0;
#pragma unroll
    for (int j = 0; j < 8; ++j) out.h[j] = f2bf(src[j]);
  } else {
    out.v = make_uint4(0u, 0u, 0u, 0u);
  }
  *(uint4*)(bp + (size_t)rowid * BSTRIDE + x0) = out.v;
}

// 640 threads = 10 waves. Wave wv: wm = wv>>1 in [0,5) owns M-tiles {2wm,2wm+1};
// wn = wv&1 owns N-tiles [5wn, 5wn+5). acc[2][5] = 40 acc regs/wave.
__global__ __launch_bounds__(640, 3)
void corr_gemm(const float* __restrict__ xo, const unsigned short* __restrict__ bpad,
               float* __restrict__ partials) {
  __shared__ __align__(16) unsigned short ldsA[2][KCLS * AROW];
  __shared__ __align__(16) unsigned short ldsB[KCLS * 16 * BSTRIDE];

  const int tid  = threadIdx.x;
  const int bid0 = blockIdx.x;
  // XCD-bijective swizzle: 256 blocks, 8 XCDs -> 32 consecutive logical blocks
  // (= 2 full batches of B) per XCD for L2 reuse of shared B rows.
  const int bid  = (bid0 & 7) * 32 + (bid0 >> 3);
  const int b    = bid >> 4;           // 16 batches
  const int y0   = (bid & 15) * TY;    // 16 groups of 14 rows

  const int lane = tid & 63;
  const int wv   = tid >> 6;           // 0..9
  const int wm   = wv >> 1;            // 0..4
  const int wn   = wv & 1;             // 0..1
  const int quad = lane >> 4;
  const int l15  = lane & 15;

  f32x4 acc[2][5];
#pragma unroll
  for (int i = 0; i < 2; ++i)
#pragma unroll
    for (int j = 0; j < 5; ++j) acc[i][j] = (f32x4){0.f, 0.f, 0.f, 0.f};

  const float* Ab = xo + (size_t)b * KCLS * HH * WW;
  const unsigned short* Bb = bpad + (size_t)b * KCLS * BPH * BSTRIDE;

  // prologue: async preload B rows y0-7..y0+7 (150 class-rows, 15 per wave)
  for (int pr = wv; pr < 15 * KCLS; pr += 10) {
    const int r15  = pr / KCLS;
    const int o    = pr - r15 * KCLS;
    const int yy   = y0 + r15;                 // row = y0-7+r15
    const int slot = (y0 - PADV + r15) & 15;
    if (lane < 29)
      glds16(Bb + ((size_t)o * BPH + yy) * BSTRIDE + lane * 8,
             ldsB + (o * 16 + slot) * BSTRIDE);
  }

  // prologue: A row y0 -> ldsA[0]
#pragma unroll
  for (int r = 0; r < 4; ++r) {
    const int t = tid + r * 640;
    if (t < KCLS * AROW) {
      const int n = t / AROW;
      const int i = t - n * AROW;
      const int x = i - PADV;
      float v = 0.f;
      if (x >= 0 && x < WW) v = Ab[((size_t)n * HH + y0) * WW + x];
      ldsA[0][t] = f2bf(v);
    }
  }
  __syncthreads();  // drains B prologue DMA + publishes A row y0

  int cur = 0;
  float va[4];
  for (int s = 0; s < TY; ++s) {
    const int y = y0 + s;
    const bool more = (s + 1 < TY);

    if (more) {
      // async DMA: B row y+8 into dead slot (one class-row per wave)
      const int yy   = y + 8 + PADV;
      const int slot = (y + 8) & 15;
      if (lane < 29)
        glds16(Bb + ((size_t)wv * BPH + yy) * BSTRIDE + lane * 8,
               ldsB + (wv * 16 + slot) * BSTRIDE);
      // register prefetch: A row y+1
      const int yl = y + 1;
#pragma unroll
      for (int r = 0; r < 4; ++r) {
        const int t = tid + r * 640;
        float v = 0.f;
        if (t < KCLS * AROW) {
          const int n = t / AROW;
          const int i = t - n * AROW;
          const int x = i - PADV;
          if (x >= 0 && x < WW) v = Ab[((size_t)n * HH + yl) * WW + x];
        }
        va[r] = v;
      }
    }

    const unsigned short* la = ldsA[cur];
#pragma unroll 1
    for (int xc = 0; xc < 7; ++xc) {
      const int x0 = xc * 32;
      bf16x8 afrag[2], bfrag[5];
      const int e0 = x0 + quad * 8 + l15;
      const int q  = e0 >> 1;
      const int sh = (e0 & 1) << 4;
#pragma unroll
      for (int mi = 0; mi < 2; ++mi) {
        const int tm = wm * 2 + mi;
        const uint32_t* pa = (const uint32_t*)la + tm * (AROW / 2);
        uint32_t w0 = pa[q], w1 = pa[q + 1], w2 = pa[q + 2],
                 w3 = pa[q + 3], w4 = pa[q + 4];
        union { uint32_t u[4]; bf16x8 v; } cv;
        cv.u[0] = __builtin_amdgcn_alignbit(w1, w0, sh);
        cv.u[1] = __builtin_amdgcn_alignbit(w2, w1, sh);
        cv.u[2] = __builtin_amdgcn_alignbit(w3, w2, sh);
        cv.u[3] = __builtin_amdgcn_alignbit(w4, w3, sh);
        afrag[mi] = cv.v;
      }
      const int slot = (y + PADV - l15) & 15;
#pragma unroll
      for (int ni = 0; ni < 5; ++ni) {
        const int to = wn * 5 + ni;
        bfrag[ni] = *(const bf16x8*)(ldsB + (to * 16 + slot) * BSTRIDE + x0 + quad * 8);
      }
#pragma unroll
      for (int mi = 0; mi < 2; ++mi)
#pragma unroll
        for (int ni = 0; ni < 5; ++ni)
          acc[mi][ni] = __builtin_amdgcn_mfma_f32_16x16x32_bf16(
              afrag[mi], bfrag[ni], acc[mi][ni], 0, 0, 0);
    }

    if (more) {
      // write A row y+1 into the other buffer; single barrier per row
      unsigned short* an = ldsA[cur ^ 1];
#pragma unroll
      for (int r = 0; r < 4; ++r) {
        const int t = tid + r * 640;
        if (t < KCLS * AROW) an[t] = f2bf(va[r]);
      }
      __syncthreads();  // drains B DMA + publishes A row y+1
      cur ^= 1;
    }
  }

  float* outp = partials + (size_t)bid * NCELL;
#pragma unroll
  for (int mi = 0; mi < 2; ++mi)
#pragma unroll
    for (int ni = 0; ni < 5; ++ni) {
      const int mrow = (wm * 2 + mi) * 16 + quad * 4;
      const int ncol = (wn * 5 + ni) * 16 + l15;
#pragma unroll
      for (int r = 0; r < 4; ++r)
        outp[(size_t)(mrow + r) * MD + ncol] = acc[mi][ni][r];
    }
}

__global__ __launch_bounds__(256)
void reduce_stage1(const float* __restrict__ partials, float* __restrict__ stage2) {
  const int c  = (blockIdx.x % 100) * 256 + threadIdx.x;
  const int pg = blockIdx.x / 100;
  const float* base = partials + (size_t)pg * 32 * NCELL + c;
  float s0 = 0.f, s1 = 0.f, s2 = 0.f, s3 = 0.f;
  for (int p = 0; p < 32; p += 4) {
    s0 += base[(size_t)(p + 0) * NCELL];
    s1 += base[(size_t)(p + 1) * NCELL];
    s2 += base[(size_t)(p + 2) * NCELL];
    s3 += base[(size_t)(p + 3) * NCELL];
  }
  stage2[(size_t)pg * NCELL + c] = (s0 + s1) + (s2 + s3);
}

__global__ __launch_bounds__(256)
void reduce_final(const float* __restrict__ stage2, float* __restrict__ Cout,
                  float* __restrict__ mins, float* __restrict__ dout) {
  const int c = blockIdx.x * 256 + threadIdx.x;
  if (blockIdx.x == 0 && threadIdx.x == 0) dout[0] = 0.f;
  double s = 0.0;
#pragma unroll
  for (int pg = 0; pg < 8; ++pg) s += (double)stage2[(size_t)pg * NCELL + c];
  const float sf = (float)s;
  Cout[c] = sf;
  const int m  = c / MD;
  const int nn = c - m * MD;
  const bool valid = ((m & 15) < TS) && ((nn & 15) < TS);
  __shared__ float red[256];
  red[threadIdx.x] = valid ? sf : 3.4e38f;
  __syncthreads();
  for (int st = 128; st > 0; st >>= 1) {
    if (threadIdx.x < st)
      red[threadIdx.x] = fminf(red[threadIdx.x], red[threadIdx.x + st]);
    __syncthreads();
  }
  if (threadIdx.x == 0) mins[blockIdx.x] = red[0];
}

__global__ __launch_bounds__(128)
void loss_kernel(const float* __restrict__ Cmat, const float* __restrict__ mins,
                 float* __restrict__ dout) {
  const int s   = blockIdx.x;
  const int dy  = s / TS;
  const int dx  = s - dy * TS;
  const int tid = threadIdx.x;
  __shared__ float fm[128];
  __shared__ double q[100];
  __shared__ double sym[100];
  __shared__ double pi[10], pj[10];
  __shared__ double red[128];

  fm[tid] = (tid < 100) ? mins[tid] : 3.4e38f;
  __syncthreads();
  for (int st = 64; st > 0; st >>= 1) {
    if (tid < st) fm[tid] = fminf(fm[tid], fm[tid + st]);
    __syncthreads();
  }
  const double minv = (double)fm[0];
  __syncthreads();

  if (tid < 100) {
    const int n = tid / 10, o = tid - (tid / 10) * 10;
    const double v = (double)Cmat[(size_t)(n * 16 + dx) * MD + (o * 16 + dy)];
    q[tid] = v - minv + LEPS;
  }
  __syncthreads();
  red[tid] = (tid < 100) ? q[tid] : 0.0;
  __syncthreads();
  for (int st = 64; st > 0; st >>= 1) {
    if (tid < st) red[tid] += red[tid + st];
    __syncthreads();
  }
  const double Z = red[0];
  __syncthreads();
  if (tid < 100) {
    const int n = tid / 10, o = tid - (tid / 10) * 10;
    sym[tid] = (q[n * 10 + o] + q[o * 10 + n]) * 0.5 / Z;
  }
  __syncthreads();
  if (tid < 10) {
    double a = 0.0, bsum = 0.0;
    for (int n2 = 0; n2 < 10; ++n2) {
      a    += sym[n2 * 10 + tid];
      bsum += sym[tid * 10 + n2];
    }
    pi[tid] = a;
    pj[tid] = bsum;
  }
  __syncthreads();
  double term = 0.0;
  if (tid < 100) {
    const int n = tid / 10, o = tid - (tid / 10) * 10;
    const double sp = sym[tid];
    term = -sp * (log(sp + LEPS) - log(pi[o] + LEPS) - log(pj[n] + LEPS));
  }
  red[tid] = term;
  __syncthreads();
  for (int st = 64; st > 0; st >>= 1) {
    if (tid < st) red[tid] += red[tid + st];
    __syncthreads();
  }
  if (tid == 0) atomicAdd(dout, (float)(red[0] / (double)(TS * TS)));
}

extern "C" void kernel_launch(void* const* d_in, const int* in_sizes, int n_in,
                              void* d_out, int out_size, void* d_ws, size_t ws_size,
                              hipStream_t stream) {
  const float* xo = (const float*)d_in[0];
  const float* xt = (const float*)d_in[1];
  float* ws       = (float*)d_ws;

  float* partials = ws;
  float* stage2   = partials + (size_t)NBLK * NCELL;
  float* Cmat     = stage2 + (size_t)8 * NCELL;
  float* mins     = Cmat + NCELL;
  unsigned short* bpad = (unsigned short*)(mins + 128);
  float* out      = (float*)d_out;

  hipLaunchKernelGGL(prep_b,        dim3(4350), dim3(256), 0, stream, xt, bpad);
  hipLaunchKernelGGL(corr_gemm,     dim3(NBLK), dim3(640), 0, stream, xo, bpad, partials);
  hipLaunchKernelGGL(reduce_stage1, dim3(800),  dim3(256), 0, stream, partials, stage2);
  hipLaunchKernelGGL(reduce_final,  dim3(100),  dim3(256), 0, stream, stage2, Cmat, mins, out);
  hipLaunchKernelGGL(loss_kernel,   dim3(225),  dim3(128), 0, stream, Cmat, mins, out);
}

// Round 2
// 150.909 us; speedup vs baseline: 1.0294x; 1.0294x over previous
//
#include <hip/hip_runtime.h>
#include <stdint.h>
#include <math.h>

// ---------------------------------------------------------------------------
// IID segmentation loss on MI355X.  Round 4.
// R3 post-mortem: LDS-read-pipe bound (~80%). A-fragment gather = 700
// ds_read_b32/row + 5M bank-conflict cycles (the dx-shift forces unaligned
// per-lane windows). R4: 8-plane shift-replicated A in LDS -> A-frag is ONE
// aligned conflict-free ds_read_b128 (plane = l15&7, base = x0+quad*8+(l15&8)).
// Planes built in registers from aligned float4 global loads (edge-masked,
// L1 absorbs the 2x overlap) + alignbit repack + b128 writes.
// Plane stride 2408 elems (1204 dw = 20 mod 32) -> 8 planes hit 8 distinct
// bank offsets -> conflict-free b128. LDS 151.3KB, 1 block/CU, 10 waves.
// ---------------------------------------------------------------------------

#define PADV 7
#define TS 15
#define KCLS 10
#define HH 224
#define WW 224
#define MD 160
#define NCELL (MD*MD)
#define NBLK 256
#define TY 14
#define BSTRIDE 232
#define BPH 240
#define PLANEE 2408          // elems per shift-plane (10*240 + 8 pad)
#define ABUFE (8*PLANEE)     // elems per A buffer (8 planes)
#define LEPS 1e-16

typedef __attribute__((ext_vector_type(4))) float f32x4;
typedef __attribute__((ext_vector_type(8))) short bf16x8;

__device__ __forceinline__ unsigned short f2bf(float f) {
  union { float f; uint32_t u; } v; v.f = f;
  return (unsigned short)((v.u + 0x7FFFu + ((v.u >> 16) & 1u)) >> 16);
}

__device__ __forceinline__ uint32_t pack2bf(float a, float b) {
  return (uint32_t)f2bf(a) | ((uint32_t)f2bf(b) << 16);
}

__device__ __forceinline__ void glds16(const unsigned short* g, unsigned short* l) {
  __builtin_amdgcn_global_load_lds(
      (const __attribute__((address_space(1))) unsigned int*)g,
      (__attribute__((address_space(3))) unsigned int*)l, 16, 0, 0);
}

// Write the 8 shift-planes for one (class, 8-elem chunk) from 16 loaded f32.
// f covers global x in [axb, axb+16) = row positions [axb+7, axb+23).
// Plane c positions [8tp, 8tp+8) hold A_row[p + c]; with axb = 8tp-8 the
// needed dword pairs fall out of w[] by alignbit.
__device__ __forceinline__ void plane_write(const f32x4 f[4], unsigned short* awr) {
  uint32_t w[8];
#pragma unroll
  for (int k = 0; k < 8; ++k)
    w[k] = pack2bf(f[k >> 1][(k & 1) * 2], f[k >> 1][(k & 1) * 2 + 1]);
#pragma unroll
  for (int c = 0; c < 8; ++c) {
    union { uint32_t u[4]; uint4 v; } o;
    if (c & 1) {
#pragma unroll
      for (int j = 0; j < 4; ++j) o.u[j] = w[j + (c + 1) / 2];
    } else {
#pragma unroll
      for (int j = 0; j < 4; ++j)
        o.u[j] = __builtin_amdgcn_alignbit(w[j + 1 + c / 2], w[j + c / 2], 16);
    }
    *(uint4*)(awr + c * PLANEE) = o.v;
  }
}

// Bpad[cls][yy][x]: cls=b*10+o, yy in [0,240) <-> row=yy-7, x in [0,232).
__global__ __launch_bounds__(256)
void prep_b(const float* __restrict__ xt, unsigned short* __restrict__ bp) {
  const int idx   = blockIdx.x * 256 + threadIdx.x;
  const int rowid = idx / 29;
  const int chunk = idx - rowid * 29;
  const int x0    = chunk * 8;
  const int yy    = rowid % BPH;
  const int cls   = rowid / BPH;
  const int row   = yy - PADV;
  union { unsigned short h[8]; uint4 v; } out;
  if (row >= 0 && row < HH && x0 < WW) {
    const float* src = xt + ((size_t)cls * HH + row) * WW + x0;
#pragma unroll
    for (int j = 0; j < 8; ++j) out.h[j] = f2bf(src[j]);
  } else {
    out.v = make_uint4(0u, 0u, 0u, 0u);
  }
  *(uint4*)(bp + (size_t)rowid * BSTRIDE + x0) = out.v;
}

// 640 threads = 10 waves; wave wv: wm=wv>>1 owns M-tiles {2wm,2wm+1},
// wn=wv&1 owns N-tiles [5wn,5wn+5). acc[2][5].
__global__ __launch_bounds__(640, 3)
void corr_gemm(const float* __restrict__ xo, const unsigned short* __restrict__ bpad,
               float* __restrict__ partials) {
  __shared__ __align__(16) unsigned short ldsA8[2 * ABUFE];
  __shared__ __align__(16) unsigned short ldsB[KCLS * 16 * BSTRIDE];

  const int tid  = threadIdx.x;
  const int bid0 = blockIdx.x;
  // XCD-bijective swizzle (256 = 8*32): 32 consecutive logical blocks per XCD.
  const int bid  = (bid0 & 7) * 32 + (bid0 >> 3);
  const int b    = bid >> 4;           // 16 batches
  const int y0   = (bid & 15) * TY;    // 16 groups of 14 rows

  const int lane = tid & 63;
  const int wv   = tid >> 6;
  const int wm   = wv >> 1;
  const int wn   = wv & 1;
  const int quad = lane >> 4;
  const int l15  = lane & 15;

  f32x4 acc[2][5];
#pragma unroll
  for (int i = 0; i < 2; ++i)
#pragma unroll
    for (int j = 0; j < 5; ++j) acc[i][j] = (f32x4){0.f, 0.f, 0.f, 0.f};

  const float* Ab = xo + (size_t)b * KCLS * HH * WW;
  const unsigned short* Bb = bpad + (size_t)b * KCLS * BPH * BSTRIDE;

  // A-row loader geometry: threads 0..299 -> (class an, chunk atp in [0,30)).
  const bool aw  = tid < 300;
  const int an   = aw ? tid / 30 : 0;
  const int atp  = aw ? tid - (tid / 30) * 30 : 0;
  const int axb  = atp * 8 - 8;        // global x of f[0].x
  bool gv[4];
#pragma unroll
  for (int g = 0; g < 4; ++g)
    gv[g] = aw && (axb + 4 * g >= 0) && (axb + 4 * g + 4 <= WW);
  unsigned short* const awr0 = ldsA8 + an * 240 + atp * 8;

  // prologue: async preload B rows y0-7..y0+7 (150 class-rows, 15/wave)
  for (int pr = wv; pr < 15 * KCLS; pr += 10) {
    const int r15  = pr / KCLS;
    const int o    = pr - r15 * KCLS;
    const int yy   = y0 + r15;                 // row = y0-7+r15
    const int slot = (y0 - PADV + r15) & 15;
    if (lane < 29)
      glds16(Bb + ((size_t)o * BPH + yy) * BSTRIDE + lane * 8,
             ldsB + (o * 16 + slot) * BSTRIDE);
  }

  // prologue: A row y0 -> planes in buf 0
  f32x4 f[4];
  {
    const float* src = Ab + ((size_t)an * HH + y0) * WW + axb;
#pragma unroll
    for (int g = 0; g < 4; ++g) {
      f[g] = (f32x4){0.f, 0.f, 0.f, 0.f};
      if (gv[g]) f[g] = *(const f32x4*)(src + 4 * g);
    }
  }
  if (aw) plane_write(f, awr0);
  __syncthreads();  // drains B prologue DMA + publishes A planes (buf 0)

  int cur = 0;
  for (int s = 0; s < TY; ++s) {
    const int y = y0 + s;
    const bool more = (s + 1 < TY);

    if (more) {
      // async DMA: B row y+8 into dead slot (one class-row per wave)
      const int yy   = y + 8 + PADV;
      const int slot = (y + 8) & 15;
      if (lane < 29)
        glds16(Bb + ((size_t)wv * BPH + yy) * BSTRIDE + lane * 8,
               ldsB + (wv * 16 + slot) * BSTRIDE);
      // issue A row y+1 global loads early (latency hides under MFMAs)
      const float* src = Ab + ((size_t)an * HH + (y + 1)) * WW + axb;
#pragma unroll
      for (int g = 0; g < 4; ++g) {
        f[g] = (f32x4){0.f, 0.f, 0.f, 0.f};
        if (gv[g]) f[g] = *(const f32x4*)(src + 4 * g);
      }
    }

    // per-lane bases: A plane read is a single aligned b128, conflict-free
    const unsigned short* paB = ldsA8 + cur * ABUFE + (l15 & 7) * PLANEE + (l15 & 8);
    const int slotB = (y + PADV - l15) & 15;

#pragma unroll 1
    for (int xc = 0; xc < 7; ++xc) {
      const int x0 = xc * 32;
      bf16x8 afrag[2], bfrag[5];
#pragma unroll
      for (int mi = 0; mi < 2; ++mi)
        afrag[mi] = *(const bf16x8*)(paB + (wm * 2 + mi) * 240 + x0 + quad * 8);
#pragma unroll
      for (int ni = 0; ni < 5; ++ni) {
        const int to = wn * 5 + ni;
        bfrag[ni] = *(const bf16x8*)(ldsB + (to * 16 + slotB) * BSTRIDE + x0 + quad * 8);
      }
#pragma unroll
      for (int mi = 0; mi < 2; ++mi)
#pragma unroll
        for (int ni = 0; ni < 5; ++ni)
          acc[mi][ni] = __builtin_amdgcn_mfma_f32_16x16x32_bf16(
              afrag[mi], bfrag[ni], acc[mi][ni], 0, 0, 0);
    }

    if (more) {
      if (aw) plane_write(f, awr0 + (cur ^ 1) * ABUFE);
      __syncthreads();  // drains B DMA + publishes A planes (buf cur^1)
      cur ^= 1;
    }
  }

  float* outp = partials + (size_t)bid * NCELL;
#pragma unroll
  for (int mi = 0; mi < 2; ++mi)
#pragma unroll
    for (int ni = 0; ni < 5; ++ni) {
      const int mrow = (wm * 2 + mi) * 16 + quad * 4;
      const int ncol = (wn * 5 + ni) * 16 + l15;
#pragma unroll
      for (int r = 0; r < 4; ++r)
        outp[(size_t)(mrow + r) * MD + ncol] = acc[mi][ni][r];
    }
}

__global__ __launch_bounds__(256)
void reduce_stage1(const float* __restrict__ partials, float* __restrict__ stage2) {
  const int c  = (blockIdx.x % 100) * 256 + threadIdx.x;
  const int pg = blockIdx.x / 100;
  const float* base = partials + (size_t)pg * 32 * NCELL + c;
  float s0 = 0.f, s1 = 0.f, s2 = 0.f, s3 = 0.f;
  for (int p = 0; p < 32; p += 4) {
    s0 += base[(size_t)(p + 0) * NCELL];
    s1 += base[(size_t)(p + 1) * NCELL];
    s2 += base[(size_t)(p + 2) * NCELL];
    s3 += base[(size_t)(p + 3) * NCELL];
  }
  stage2[(size_t)pg * NCELL + c] = (s0 + s1) + (s2 + s3);
}

__global__ __launch_bounds__(256)
void reduce_final(const float* __restrict__ stage2, float* __restrict__ Cout,
                  float* __restrict__ mins, float* __restrict__ dout) {
  const int c = blockIdx.x * 256 + threadIdx.x;
  if (blockIdx.x == 0 && threadIdx.x == 0) dout[0] = 0.f;
  double s = 0.0;
#pragma unroll
  for (int pg = 0; pg < 8; ++pg) s += (double)stage2[(size_t)pg * NCELL + c];
  const float sf = (float)s;
  Cout[c] = sf;
  const int m  = c / MD;
  const int nn = c - m * MD;
  const bool valid = ((m & 15) < TS) && ((nn & 15) < TS);
  __shared__ float red[256];
  red[threadIdx.x] = valid ? sf : 3.4e38f;
  __syncthreads();
  for (int st = 128; st > 0; st >>= 1) {
    if (threadIdx.x < st)
      red[threadIdx.x] = fminf(red[threadIdx.x], red[threadIdx.x + st]);
    __syncthreads();
  }
  if (threadIdx.x == 0) mins[blockIdx.x] = red[0];
}

__global__ __launch_bounds__(128)
void loss_kernel(const float* __restrict__ Cmat, const float* __restrict__ mins,
                 float* __restrict__ dout) {
  const int s   = blockIdx.x;
  const int dy  = s / TS;
  const int dx  = s - dy * TS;
  const int tid = threadIdx.x;
  __shared__ float fm[128];
  __shared__ double q[100];
  __shared__ double sym[100];
  __shared__ double pi[10], pj[10];
  __shared__ double red[128];

  fm[tid] = (tid < 100) ? mins[tid] : 3.4e38f;
  __syncthreads();
  for (int st = 64; st > 0; st >>= 1) {
    if (tid < st) fm[tid] = fminf(fm[tid], fm[tid + st]);
    __syncthreads();
  }
  const double minv = (double)fm[0];
  __syncthreads();

  if (tid < 100) {
    const int n = tid / 10, o = tid - (tid / 10) * 10;
    const double v = (double)Cmat[(size_t)(n * 16 + dx) * MD + (o * 16 + dy)];
    q[tid] = v - minv + LEPS;
  }
  __syncthreads();
  red[tid] = (tid < 100) ? q[tid] : 0.0;
  __syncthreads();
  for (int st = 64; st > 0; st >>= 1) {
    if (tid < st) red[tid] += red[tid + st];
    __syncthreads();
  }
  const double Z = red[0];
  __syncthreads();
  if (tid < 100) {
    const int n = tid / 10, o = tid - (tid / 10) * 10;
    sym[tid] = (q[n * 10 + o] + q[o * 10 + n]) * 0.5 / Z;
  }
  __syncthreads();
  if (tid < 10) {
    double a = 0.0, bsum = 0.0;
    for (int n2 = 0; n2 < 10; ++n2) {
      a    += sym[n2 * 10 + tid];
      bsum += sym[tid * 10 + n2];
    }
    pi[tid] = a;
    pj[tid] = bsum;
  }
  __syncthreads();
  double term = 0.0;
  if (tid < 100) {
    const int n = tid / 10, o = tid - (tid / 10) * 10;
    const double sp = sym[tid];
    term = -sp * (log(sp + LEPS) - log(pi[o] + LEPS) - log(pj[n] + LEPS));
  }
  red[tid] = term;
  __syncthreads();
  for (int st = 64; st > 0; st >>= 1) {
    if (tid < st) red[tid] += red[tid + st];
    __syncthreads();
  }
  if (tid == 0) atomicAdd(dout, (float)(red[0] / (double)(TS * TS)));
}

extern "C" void kernel_launch(void* const* d_in, const int* in_sizes, int n_in,
                              void* d_out, int out_size, void* d_ws, size_t ws_size,
                              hipStream_t stream) {
  const float* xo = (const float*)d_in[0];
  const float* xt = (const float*)d_in[1];
  float* ws       = (float*)d_ws;

  float* partials = ws;
  float* stage2   = partials + (size_t)NBLK * NCELL;
  float* Cmat     = stage2 + (size_t)8 * NCELL;
  float* mins     = Cmat + NCELL;
  unsigned short* bpad = (unsigned short*)(mins + 128);
  float* out      = (float*)d_out;

  hipLaunchKernelGGL(prep_b,        dim3(4350), dim3(256), 0, stream, xt, bpad);
  hipLaunchKernelGGL(corr_gemm,     dim3(NBLK), dim3(640), 0, stream, xo, bpad, partials);
  hipLaunchKernelGGL(reduce_stage1, dim3(800),  dim3(256), 0, stream, partials, stage2);
  hipLaunchKernelGGL(reduce_final,  dim3(100),  dim3(256), 0, stream, stage2, Cmat, mins, out);
  hipLaunchKernelGGL(loss_kernel,   dim3(225),  dim3(128), 0, stream, Cmat, mins, out);
}